// Round 2
// 427.798 us; speedup vs baseline: 1.0524x; 1.0524x over previous
//
#include <hip/hip_runtime.h>

typedef int v4i __attribute__((ext_vector_type(4)));
typedef int v16i __attribute__((ext_vector_type(16)));

#define EPS_F 1e-8f

#define GLOAD_LDS16(g, l)                                              \
    __builtin_amdgcn_global_load_lds(                                  \
        (const __attribute__((address_space(1))) void*)(g),            \
        (__attribute__((address_space(3))) void*)(l), 16, 0, 0)

// ---------------- kernel 1: sum |w| in fp64 ----------------
__global__ void __launch_bounds__(256) wabs_sum_kernel(const float* __restrict__ w,
                                                       double* __restrict__ out, int n4) {
    const float4* w4 = (const float4*)w;
    double s = 0.0;
    int idx = blockIdx.x * 256 + threadIdx.x;
    int stride = gridDim.x * 256;
    for (int i = idx; i < n4; i += stride) {
        float4 v = w4[i];
        s += (double)fabsf(v.x) + (double)fabsf(v.y) +
             (double)fabsf(v.z) + (double)fabsf(v.w);
    }
    for (int off = 32; off > 0; off >>= 1)
        s += __shfl_down(s, off);
    __shared__ double sm[4];
    if ((threadIdx.x & 63) == 0) sm[threadIdx.x >> 6] = s;
    __syncthreads();
    if (threadIdx.x == 0) {
        atomicAdd(out, sm[0] + sm[1] + sm[2] + sm[3]);
    }
}

// ---------------- kernel 2: ternary-quantize W -> int8 ----------------
__global__ void __launch_bounds__(256) wquant_kernel(const float* __restrict__ w,
                                                     const double* __restrict__ wsum,
                                                     signed char* __restrict__ wq,
                                                     int n4, int n) {
    float wsf = (float)(wsum[0] / (double)n) + EPS_F;
    float inv = 1.0f / wsf;
    const float4* w4 = (const float4*)w;
    unsigned int* q4 = (unsigned int*)wq;
    int idx = blockIdx.x * 256 + threadIdx.x;
    int stride = gridDim.x * 256;
    for (int i = idx; i < n4; i += stride) {
        float4 v = w4[i];
        int q0 = min(1, max(-1, (int)rintf(v.x * inv)));
        int q1 = min(1, max(-1, (int)rintf(v.y * inv)));
        int q2 = min(1, max(-1, (int)rintf(v.z * inv)));
        int q3 = min(1, max(-1, (int)rintf(v.w * inv)));
        q4[i] = (q0 & 0xff) | ((q1 & 0xff) << 8) | ((q2 & 0xff) << 16) | ((q3 & 0xff) << 24);
    }
}

// ---------------- kernel 3: per-token int8 activation quant ----------------
__global__ void __launch_bounds__(256) xquant_kernel(const float* __restrict__ x,
                                                     signed char* __restrict__ xq,
                                                     float* __restrict__ xscale, int K) {
    int row = blockIdx.x;
    const float4* xr = (const float4*)(x + (size_t)row * K);
    unsigned int* qr = (unsigned int*)(xq + (size_t)row * K);
    int t = threadIdx.x;
    float4 v[4];
    float mx = 0.0f;
#pragma unroll
    for (int j = 0; j < 4; j++) {
        v[j] = xr[t + j * 256];
        mx = fmaxf(mx, fmaxf(fmaxf(fabsf(v[j].x), fabsf(v[j].y)),
                             fmaxf(fabsf(v[j].z), fabsf(v[j].w))));
    }
    for (int off = 32; off > 0; off >>= 1)
        mx = fmaxf(mx, __shfl_down(mx, off));
    __shared__ float sm[4];
    if ((t & 63) == 0) sm[t >> 6] = mx;
    __syncthreads();
    float scale = fmaxf(fmaxf(fmaxf(sm[0], sm[1]), fmaxf(sm[2], sm[3])), EPS_F);
    float inv = 127.0f / scale;
#pragma unroll
    for (int j = 0; j < 4; j++) {
        int q0 = min(127, max(-127, (int)rintf(v[j].x * inv)));
        int q1 = min(127, max(-127, (int)rintf(v[j].y * inv)));
        int q2 = min(127, max(-127, (int)rintf(v[j].z * inv)));
        int q3 = min(127, max(-127, (int)rintf(v[j].w * inv)));
        qr[t + j * 256] = (q0 & 0xff) | ((q1 & 0xff) << 8) | ((q2 & 0xff) << 16) | ((q3 & 0xff) << 24);
    }
    if (t == 0) xscale[row] = scale;
}

// ---------------- kernel 4: int8 MFMA GEMM, 256x256 tile, 8-phase pipeline ----------------
// 512 threads = 8 waves (2M x 4N). Per-wave output 128x64 = 4x2 tiles of 32x32.
// BK=128 (128B rows). LDS: [buf(2)][A/B][khalf(2)] regions of 16KB = 128KB total.
// Region layout: seg(row, c) = row*4 + (c ^ ((row>>1)&3)), c = 16B chunk within khalf.
//   -> bank-slot = seg&7 = (row&1)*4 + (c ^ ((row>>1)&3)): 8 consecutive rows cover
//      all 8 slots -> conflict-free ds_read_b128. Swizzle applied on the GLOBAL
//      source addr (global_load_lds dest is lane-linear, rule #21).
// Schedule per iteration (2 K-tiles TE->buf0, TO->buf1), phases P0..P7:
//   compute: P0(b0,h0,mt01+B) P1(b0,h0,mt23) P2(b0,h1,mt01+B) P3(b0,h1,mt23)
//            P4(b1,h0,mt01+B) P5(b1,h0,mt23) P6(b1,h1,mt01+B) P7(b1,h1,mt23)
//   stage:   P0:A(b1,h1,TO) P1:B(b0,h0,TE') P2:A(b0,h0,TE') P3:B(b0,h1,TE')
//            P4:A(b0,h1,TE') P5:B(b1,h0,TO') P6:A(b1,h0,TO') P7:B(b1,h1,TO')
//   each staged region was fully consumed in the previous phase; vmcnt(6) only at
//   P3/P7 (2 loads/phase * 3 phases in flight) -- loads never drain to 0 in-loop.
__global__ void __launch_bounds__(512, 2) gemm_i8_kernel(const signed char* __restrict__ Aq,
                                                         const signed char* __restrict__ Bq,
                                                         const float* __restrict__ xscale,
                                                         const double* __restrict__ wsum,
                                                         float* __restrict__ C,
                                                         int M, int N, int K, int wcount) {
    constexpr int BM = 256, BN = 256, BK = 128;
    __shared__ __align__(16) signed char As[2 * 2 * 16384];
    __shared__ __align__(16) signed char Bs[2 * 2 * 16384];

    const int tid = threadIdx.x;
    const int wave = tid >> 6;
    const int lane = tid & 63;
    const int l32 = lane & 31;
    const int half = lane >> 5;
    const int waveM = (wave & 1) * 128;
    const int waveN = (wave >> 1) * 64;

    // XCD-aware bijective block swizzle (512 blocks, 512 % 8 == 0)
    const int nbx = gridDim.x;
    const int nwg = nbx * gridDim.y;
    const int bid = blockIdx.y * nbx + blockIdx.x;
    const int cpx = nwg >> 3;
    const int swzb = (bid & 7) * cpx + (bid >> 3);
    const int bm = (swzb / nbx) * BM;
    const int bn = (swzb % nbx) * BN;

    v16i acc[4][2];
#pragma unroll
    for (int mt = 0; mt < 4; mt++)
#pragma unroll
        for (int nt = 0; nt < 2; nt++)
#pragma unroll
            for (int r = 0; r < 16; r++) acc[mt][nt][r] = 0;

    // ---- staging precompute: wave w covers segs [w*128, w*128+128) of each region ----
    const int segA0 = wave * 128 + lane;
    const int segA1 = wave * 128 + 64 + lane;
    const int rS0 = segA0 >> 2, rS1 = segA1 >> 2;
    const int cS0 = (segA0 & 3) ^ ((rS0 >> 1) & 3);
    const int cS1 = (segA1 & 3) ^ ((rS1 >> 1) & 3);
    const signed char* aSrc0 = Aq + (size_t)(bm + rS0) * K + cS0 * 16;
    const signed char* aSrc1 = Aq + (size_t)(bm + rS1) * K + cS1 * 16;
    const signed char* bSrc0 = Bq + (size_t)(bn + rS0) * K + cS0 * 16;
    const signed char* bSrc1 = Bq + (size_t)(bn + rS1) * K + cS1 * 16;
    const int dOff0 = segA0 * 16;
    const int dOff1 = segA1 * 16;

#define REG_A(b, H) (As + ((b) * 2 + (H)) * 16384)
#define REG_B(b, H) (Bs + ((b) * 2 + (H)) * 16384)
#define STAGE_A(b, H, k0) {                                            \
        GLOAD_LDS16(aSrc0 + (k0) + (H) * 64, REG_A(b, H) + dOff0);     \
        GLOAD_LDS16(aSrc1 + (k0) + (H) * 64, REG_A(b, H) + dOff1); }
#define STAGE_B(b, H, k0) {                                            \
        GLOAD_LDS16(bSrc0 + (k0) + (H) * 64, REG_B(b, H) + dOff0);     \
        GLOAD_LDS16(bSrc1 + (k0) + (H) * 64, REG_B(b, H) + dOff1); }

    // ---- fragment read offsets (16B-seg units); swizzle dep on l32 only ----
    const int swzl = (l32 >> 1) & 3;
    const int cx0 = half ^ swzl;            // k-chunk parity 0 within half
    const int cx1 = cx0 ^ 2;                // k-chunk parity 1 within half
    const int a0off = (waveM + l32) * 4 + cx0;
    const int a1off = (waveM + l32) * 4 + cx1;
    const int b0off = (waveN + l32) * 4 + cx0;
    const int b1off = (waveN + l32) * 4 + cx1;

    v4i b00 = {}, b01 = {}, b10 = {}, b11 = {};

#define MFMA8(mtb)                                                                                   \
    acc[mtb][0]       = __builtin_amdgcn_mfma_i32_32x32x32_i8(a0_, b00, acc[mtb][0], 0, 0, 0);       \
    acc[mtb][1]       = __builtin_amdgcn_mfma_i32_32x32x32_i8(a0_, b10, acc[mtb][1], 0, 0, 0);       \
    acc[(mtb) + 1][0] = __builtin_amdgcn_mfma_i32_32x32x32_i8(a2_, b00, acc[(mtb) + 1][0], 0, 0, 0); \
    acc[(mtb) + 1][1] = __builtin_amdgcn_mfma_i32_32x32x32_i8(a2_, b10, acc[(mtb) + 1][1], 0, 0, 0); \
    acc[mtb][0]       = __builtin_amdgcn_mfma_i32_32x32x32_i8(a1_, b01, acc[mtb][0], 0, 0, 0);       \
    acc[mtb][1]       = __builtin_amdgcn_mfma_i32_32x32x32_i8(a1_, b11, acc[mtb][1], 0, 0, 0);       \
    acc[(mtb) + 1][0] = __builtin_amdgcn_mfma_i32_32x32x32_i8(a3_, b01, acc[(mtb) + 1][0], 0, 0, 0); \
    acc[(mtb) + 1][1] = __builtin_amdgcn_mfma_i32_32x32x32_i8(a3_, b11, acc[(mtb) + 1][1], 0, 0, 0);

#define PHASE(b, H, mtb, LOADB, STAGE_STMT, VMC)                        \
    {                                                                   \
        const v4i* Ap = (const v4i*)REG_A(b, H);                        \
        const v4i* Bp = (const v4i*)REG_B(b, H);                        \
        v4i a0_ = Ap[a0off + (mtb)*128];                                \
        v4i a1_ = Ap[a1off + (mtb)*128];                                \
        v4i a2_ = Ap[a0off + ((mtb) + 1) * 128];                        \
        v4i a3_ = Ap[a1off + ((mtb) + 1) * 128];                        \
        if (LOADB) {                                                    \
            b00 = Bp[b0off];       b01 = Bp[b1off];                     \
            b10 = Bp[b0off + 128]; b11 = Bp[b1off + 128];               \
        }                                                               \
        STAGE_STMT;                                                     \
        __builtin_amdgcn_s_barrier();                                   \
        asm volatile("s_waitcnt lgkmcnt(0)" ::: "memory");              \
        __builtin_amdgcn_sched_barrier(0);                              \
        __builtin_amdgcn_s_setprio(1);                                  \
        MFMA8(mtb);                                                     \
        __builtin_amdgcn_s_setprio(0);                                  \
        if (VMC) { asm volatile("s_waitcnt vmcnt(6)" ::: "memory"); }   \
        __builtin_amdgcn_s_barrier();                                   \
    }

    // ---- prologue: T0 fully + T1 minus its A-high (completed by it0/P0) ----
    STAGE_B(0, 0, 0); STAGE_A(0, 0, 0); STAGE_B(0, 1, 0); STAGE_A(0, 1, 0);
    STAGE_B(1, 0, BK); STAGE_A(1, 0, BK); STAGE_B(1, 1, BK);
    asm volatile("s_waitcnt vmcnt(6)" ::: "memory");
    __builtin_amdgcn_s_barrier();

    const int kclamp = K - BK;   // clamp garbage prefetch of tiles past K in-bounds
    const int niter = K / (2 * BK);
#pragma unroll 1
    for (int it = 0; it < niter; ++it) {
        int k0O = (2 * it + 1) * BK;
        int k0E2 = (2 * it + 2) * BK; if (k0E2 > kclamp) k0E2 = kclamp;
        int k0O2 = (2 * it + 3) * BK; if (k0O2 > kclamp) k0O2 = kclamp;

        PHASE(0, 0, 0, 1, STAGE_A(1, 1, k0O), 0)
        PHASE(0, 0, 2, 0, STAGE_B(0, 0, k0E2), 0)
        PHASE(0, 1, 0, 1, STAGE_A(0, 0, k0E2), 0)
        PHASE(0, 1, 2, 0, STAGE_B(0, 1, k0E2), 1)
        PHASE(1, 0, 0, 1, STAGE_A(0, 1, k0E2), 0)
        PHASE(1, 0, 2, 0, STAGE_B(1, 0, k0O2), 0)
        PHASE(1, 1, 0, 1, STAGE_A(1, 0, k0O2), 0)
        PHASE(1, 1, 2, 0, STAGE_B(1, 1, k0O2), 1)
    }

    // ---- epilogue: 32x32 C/D layout: col = lane&31, row = (r&3) + 8*(r>>2) + 4*half
    float wsf = (float)(wsum[0] / (double)wcount) + EPS_F;
    const float wk = wsf / 127.0f;
#pragma unroll
    for (int mt = 0; mt < 4; mt++) {
        int rowbase = bm + waveM + mt * 32 + 4 * half;
#pragma unroll
        for (int r = 0; r < 16; r++) {
            int gm = rowbase + (r & 3) + 8 * (r >> 2);
            float s = xscale[gm] * wk;
            float* crow = C + (size_t)gm * N + bn + waveN + l32;
            crow[0]  = (float)acc[mt][0][r] * s;
            crow[32] = (float)acc[mt][1][r] * s;
        }
    }
}

extern "C" void kernel_launch(void* const* d_in, const int* in_sizes, int n_in,
                              void* d_out, int out_size, void* d_ws, size_t ws_size,
                              hipStream_t stream) {
    const float* x = (const float*)d_in[0];
    const float* w = (const float*)d_in[1];
    float* y = (float*)d_out;

    const int K = 4096, N = 4096;
    const int M = in_sizes[0] / K;       // 8192
    const int wcount = in_sizes[1];      // N*K

    double* wsum = (double*)d_ws;
    float* xscale = (float*)((char*)d_ws + 256);
    signed char* xq = (signed char*)((char*)d_ws + 256 + 65536);
    signed char* wq = xq + (size_t)M * K;

    hipMemsetAsync(wsum, 0, sizeof(double), stream);
    wabs_sum_kernel<<<1024, 256, 0, stream>>>(w, wsum, wcount / 4);
    wquant_kernel<<<1024, 256, 0, stream>>>(w, wsum, wq, wcount / 4, wcount);
    xquant_kernel<<<M, 256, 0, stream>>>(x, xq, xscale, K);
    dim3 grid(N / 256, M / 256);
    gemm_i8_kernel<<<grid, 512, 0, stream>>>(xq, wq, xscale, wsum, y, M, N, K, wcount);
}

// Round 4
// 419.272 us; speedup vs baseline: 1.0738x; 1.0203x over previous
//
#include <hip/hip_runtime.h>

typedef int v4i __attribute__((ext_vector_type(4)));
typedef int v16i __attribute__((ext_vector_type(16)));

#define EPS_F 1e-8f

#define GLOAD_LDS16(g, l)                                              \
    __builtin_amdgcn_global_load_lds(                                  \
        (const __attribute__((address_space(1))) void*)(g),            \
        (__attribute__((address_space(3))) void*)(l), 16, 0, 0)

// ---------------- kernel 1: fused |w|-sum (blocks [0,1024)) + per-token x quant ----------------
__global__ void __launch_bounds__(256) wabs_xquant_kernel(const float* __restrict__ w,
                                                          double* __restrict__ out, int n4,
                                                          const float* __restrict__ x,
                                                          signed char* __restrict__ xq,
                                                          float* __restrict__ xscale, int K) {
    if (blockIdx.x < 1024) {
        // ---- |w| fp64 sum ----
        const float4* w4 = (const float4*)w;
        double s = 0.0;
        int idx = blockIdx.x * 256 + threadIdx.x;
        int stride = 1024 * 256;
        for (int i = idx; i < n4; i += stride) {
            float4 v = w4[i];
            s += (double)fabsf(v.x) + (double)fabsf(v.y) +
                 (double)fabsf(v.z) + (double)fabsf(v.w);
        }
        for (int off = 32; off > 0; off >>= 1)
            s += __shfl_down(s, off);
        __shared__ double smd[4];
        if ((threadIdx.x & 63) == 0) smd[threadIdx.x >> 6] = s;
        __syncthreads();
        if (threadIdx.x == 0) {
            atomicAdd(out, smd[0] + smd[1] + smd[2] + smd[3]);
        }
    } else {
        // ---- per-token int8 activation quant, one row per block ----
        int row = blockIdx.x - 1024;
        const float4* xr = (const float4*)(x + (size_t)row * K);
        unsigned int* qr = (unsigned int*)(xq + (size_t)row * K);
        int t = threadIdx.x;
        float4 v[4];
        float mx = 0.0f;
#pragma unroll
        for (int j = 0; j < 4; j++) {
            v[j] = xr[t + j * 256];
            mx = fmaxf(mx, fmaxf(fmaxf(fabsf(v[j].x), fabsf(v[j].y)),
                                 fmaxf(fabsf(v[j].z), fabsf(v[j].w))));
        }
        for (int off = 32; off > 0; off >>= 1)
            mx = fmaxf(mx, __shfl_down(mx, off));
        __shared__ float smf[4];
        if ((t & 63) == 0) smf[t >> 6] = mx;
        __syncthreads();
        float scale = fmaxf(fmaxf(fmaxf(smf[0], smf[1]), fmaxf(smf[2], smf[3])), EPS_F);
        float inv = 127.0f / scale;
#pragma unroll
        for (int j = 0; j < 4; j++) {
            int q0 = min(127, max(-127, (int)rintf(v[j].x * inv)));
            int q1 = min(127, max(-127, (int)rintf(v[j].y * inv)));
            int q2 = min(127, max(-127, (int)rintf(v[j].z * inv)));
            int q3 = min(127, max(-127, (int)rintf(v[j].w * inv)));
            qr[t + j * 256] = (q0 & 0xff) | ((q1 & 0xff) << 8) | ((q2 & 0xff) << 16) | ((q3 & 0xff) << 24);
        }
        if (t == 0) xscale[row] = scale;
    }
}

// ---------------- kernel 2: ternary-quantize W -> int8 ----------------
__global__ void __launch_bounds__(256) wquant_kernel(const float* __restrict__ w,
                                                     const double* __restrict__ wsum,
                                                     signed char* __restrict__ wq,
                                                     int n4, int n) {
    float wsf = (float)(wsum[0] / (double)n) + EPS_F;
    float inv = 1.0f / wsf;
    const float4* w4 = (const float4*)w;
    unsigned int* q4 = (unsigned int*)wq;
    int idx = blockIdx.x * 256 + threadIdx.x;
    int stride = gridDim.x * 256;
    for (int i = idx; i < n4; i += stride) {
        float4 v = w4[i];
        int q0 = min(1, max(-1, (int)rintf(v.x * inv)));
        int q1 = min(1, max(-1, (int)rintf(v.y * inv)));
        int q2 = min(1, max(-1, (int)rintf(v.z * inv)));
        int q3 = min(1, max(-1, (int)rintf(v.w * inv)));
        q4[i] = (q0 & 0xff) | ((q1 & 0xff) << 8) | ((q2 & 0xff) << 16) | ((q3 & 0xff) << 24);
    }
}

// ---------------- kernel 3: int8 MFMA GEMM, 256x256 tile, 4-phase / 1-barrier ----------------
// 512 threads = 8 waves (2M x 4N). Per-wave output 128x64 = 4x2 tiles of 32x32.
// BK=128. LDS: [buf(2)][A/B][khalf(2)] regions of 16KB = 128KB total (1 block/CU).
// Region layout: seg(row, c) = row*4 + (c ^ ((row>>1)&3)) -> bank-slot seg&7 covers
// all 8 slots per 8 rows -> conflict-free ds_read_b128 (verified r2: conflicts at b128 floor).
// ONE barrier per phase (r3 post-mortem): s_barrier does not wait on issued MFMAs,
// so phase-n+1 ds_reads overlap phase-n MFMA drain. WAR safety: every ds_read feeds
// an MFMA in the same phase (compiler lgkm waits) => reads complete before the wave
// reaches the end barrier; the overwriting stage is issued after it.
// RAW safety: vmcnt(8) at phase end completes the 3-phase-old stage group (12 in
// flight, oldest 4), barrier publishes, fence-asm prevents read hoist above barrier.
//   P0: compute(0,0) stage(1,1,TO)   P1: compute(0,1) stage(0,0,TE')
//   P2: compute(1,0) stage(0,1,TE')  P3: compute(1,1) stage(1,0,TO')
__global__ void __launch_bounds__(512, 2) gemm_i8_kernel(const signed char* __restrict__ Aq,
                                                         const signed char* __restrict__ Bq,
                                                         const float* __restrict__ xscale,
                                                         const double* __restrict__ wsum,
                                                         float* __restrict__ C,
                                                         int M, int N, int K, int wcount) {
    constexpr int BM = 256, BN = 256, BK = 128;
    __shared__ __align__(16) signed char As[2 * 2 * 16384];
    __shared__ __align__(16) signed char Bs[2 * 2 * 16384];

    const int tid = threadIdx.x;
    const int wave = tid >> 6;
    const int lane = tid & 63;
    const int l32 = lane & 31;
    const int half = lane >> 5;
    const int waveM = (wave & 1) * 128;
    const int waveN = (wave >> 1) * 64;

    // XCD-aware bijective block swizzle (512 blocks, 512 % 8 == 0)
    const int nbx = gridDim.x;
    const int nwg = nbx * gridDim.y;
    const int bid = blockIdx.y * nbx + blockIdx.x;
    const int cpx = nwg >> 3;
    const int swzb = (bid & 7) * cpx + (bid >> 3);
    const int bm = (swzb / nbx) * BM;
    const int bn = (swzb % nbx) * BN;

    v16i acc[4][2];
#pragma unroll
    for (int mt = 0; mt < 4; mt++)
#pragma unroll
        for (int nt = 0; nt < 2; nt++)
#pragma unroll
            for (int r = 0; r < 16; r++) acc[mt][nt][r] = 0;

    // ---- staging precompute: wave w covers segs [w*128, w*128+128) of each region ----
    const int segA0 = wave * 128 + lane;
    const int segA1 = wave * 128 + 64 + lane;
    const int rS0 = segA0 >> 2, rS1 = segA1 >> 2;
    const int cS0 = (segA0 & 3) ^ ((rS0 >> 1) & 3);
    const int cS1 = (segA1 & 3) ^ ((rS1 >> 1) & 3);
    const signed char* aSrc0 = Aq + (size_t)(bm + rS0) * K + cS0 * 16;
    const signed char* aSrc1 = Aq + (size_t)(bm + rS1) * K + cS1 * 16;
    const signed char* bSrc0 = Bq + (size_t)(bn + rS0) * K + cS0 * 16;
    const signed char* bSrc1 = Bq + (size_t)(bn + rS1) * K + cS1 * 16;
    const int dOff0 = segA0 * 16;
    const int dOff1 = segA1 * 16;

#define REG_A(b, H) (As + ((b) * 2 + (H)) * 16384)
#define REG_B(b, H) (Bs + ((b) * 2 + (H)) * 16384)
#define STAGE_A(b, H, k0) {                                            \
        GLOAD_LDS16(aSrc0 + (k0) + (H) * 64, REG_A(b, H) + dOff0);     \
        GLOAD_LDS16(aSrc1 + (k0) + (H) * 64, REG_A(b, H) + dOff1); }
#define STAGE_B(b, H, k0) {                                            \
        GLOAD_LDS16(bSrc0 + (k0) + (H) * 64, REG_B(b, H) + dOff0);     \
        GLOAD_LDS16(bSrc1 + (k0) + (H) * 64, REG_B(b, H) + dOff1); }

    // ---- fragment read offsets (16B-seg units); swizzle dep on l32 only ----
    const int swzl = (l32 >> 1) & 3;
    const int cx0 = half ^ swzl;            // k-chunk parity 0 within half
    const int cx1 = cx0 ^ 2;                // k-chunk parity 1 within half
    const int a0off = (waveM + l32) * 4 + cx0;
    const int a1off = (waveM + l32) * 4 + cx1;
    const int b0off = (waveN + l32) * 4 + cx0;
    const int b1off = (waveN + l32) * 4 + cx1;

#define MFMA_I8(a, b, c) __builtin_amdgcn_mfma_i32_32x32x32_i8(a, b, c, 0, 0, 0)

#define PHASE1B(b, H, STAGE_STMT)                                       \
    {                                                                   \
        const v4i* Ap = (const v4i*)REG_A(b, H);                        \
        const v4i* Bp = (const v4i*)REG_B(b, H);                        \
        v4i aA0 = Ap[a0off];       v4i aA1 = Ap[a0off + 128];           \
        v4i aA2 = Ap[a0off + 256]; v4i aA3 = Ap[a0off + 384];           \
        v4i bA0 = Bp[b0off];       v4i bA1 = Bp[b0off + 128];           \
        v4i aB0 = Ap[a1off];       v4i aB1 = Ap[a1off + 128];           \
        v4i aB2 = Ap[a1off + 256]; v4i aB3 = Ap[a1off + 384];           \
        v4i bB0 = Bp[b1off];       v4i bB1 = Bp[b1off + 128];           \
        STAGE_STMT;                                                     \
        __builtin_amdgcn_s_setprio(1);                                  \
        acc[0][0] = MFMA_I8(aA0, bA0, acc[0][0]);                       \
        acc[0][1] = MFMA_I8(aA0, bA1, acc[0][1]);                       \
        acc[1][0] = MFMA_I8(aA1, bA0, acc[1][0]);                       \
        acc[1][1] = MFMA_I8(aA1, bA1, acc[1][1]);                       \
        acc[2][0] = MFMA_I8(aA2, bA0, acc[2][0]);                       \
        acc[2][1] = MFMA_I8(aA2, bA1, acc[2][1]);                       \
        acc[3][0] = MFMA_I8(aA3, bA0, acc[3][0]);                       \
        acc[3][1] = MFMA_I8(aA3, bA1, acc[3][1]);                       \
        acc[0][0] = MFMA_I8(aB0, bB0, acc[0][0]);                       \
        acc[0][1] = MFMA_I8(aB0, bB1, acc[0][1]);                       \
        acc[1][0] = MFMA_I8(aB1, bB0, acc[1][0]);                       \
        acc[1][1] = MFMA_I8(aB1, bB1, acc[1][1]);                       \
        acc[2][0] = MFMA_I8(aB2, bB0, acc[2][0]);                       \
        acc[2][1] = MFMA_I8(aB2, bB1, acc[2][1]);                       \
        acc[3][0] = MFMA_I8(aB3, bB0, acc[3][0]);                       \
        acc[3][1] = MFMA_I8(aB3, bB1, acc[3][1]);                       \
        __builtin_amdgcn_s_setprio(0);                                  \
        asm volatile("s_waitcnt vmcnt(8)" ::: "memory");                \
        __builtin_amdgcn_s_barrier();                                   \
        asm volatile("" ::: "memory");                                  \
    }

    // ---- prologue: stage regions for P0, P1, P2 (3-phase lookahead) ----
    STAGE_A(0, 0, 0); STAGE_B(0, 0, 0);
    STAGE_A(0, 1, 0); STAGE_B(0, 1, 0);
    STAGE_A(1, 0, BK); STAGE_B(1, 0, BK);
    asm volatile("s_waitcnt vmcnt(8)" ::: "memory");
    __builtin_amdgcn_s_barrier();
    asm volatile("" ::: "memory");

    const int kclamp = K - BK;   // clamp garbage prefetch of tiles past K in-bounds
    const int niter = K / (2 * BK);
#pragma unroll 1
    for (int it = 0; it < niter; ++it) {
        int k0O = (2 * it + 1) * BK;                                  // always <= K-BK
        int k0E2 = (2 * it + 2) * BK; if (k0E2 > kclamp) k0E2 = kclamp;
        int k0O2 = (2 * it + 3) * BK; if (k0O2 > kclamp) k0O2 = kclamp;

        PHASE1B(0, 0, STAGE_A(1, 1, k0O);  STAGE_B(1, 1, k0O))
        PHASE1B(0, 1, STAGE_A(0, 0, k0E2); STAGE_B(0, 0, k0E2))
        PHASE1B(1, 0, STAGE_A(0, 1, k0E2); STAGE_B(0, 1, k0E2))
        PHASE1B(1, 1, STAGE_A(1, 0, k0O2); STAGE_B(1, 0, k0O2))
    }

    // drain zombie global_load_lds before LDS deallocates at endpgm
    asm volatile("s_waitcnt vmcnt(0)" ::: "memory");

    // ---- epilogue: 32x32 C/D layout: col = lane&31, row = (r&3) + 8*(r>>2) + 4*half
    float wsf = (float)(wsum[0] / (double)wcount) + EPS_F;
    const float wk = wsf / 127.0f;
#pragma unroll
    for (int mt = 0; mt < 4; mt++) {
        int rowbase = bm + waveM + mt * 32 + 4 * half;
#pragma unroll
        for (int r = 0; r < 16; r++) {
            int gm = rowbase + (r & 3) + 8 * (r >> 2);
            float s = xscale[gm] * wk;
            float* crow = C + (size_t)gm * N + bn + waveN + l32;
            crow[0]  = (float)acc[mt][0][r] * s;
            crow[32] = (float)acc[mt][1][r] * s;
        }
    }
}

extern "C" void kernel_launch(void* const* d_in, const int* in_sizes, int n_in,
                              void* d_out, int out_size, void* d_ws, size_t ws_size,
                              hipStream_t stream) {
    const float* x = (const float*)d_in[0];
    const float* w = (const float*)d_in[1];
    float* y = (float*)d_out;

    const int K = 4096, N = 4096;
    const int M = in_sizes[0] / K;       // 8192
    const int wcount = in_sizes[1];      // N*K

    double* wsum = (double*)d_ws;
    float* xscale = (float*)((char*)d_ws + 256);
    signed char* xq = (signed char*)((char*)d_ws + 256 + 65536);
    signed char* wq = xq + (size_t)M * K;

    hipMemsetAsync(wsum, 0, sizeof(double), stream);
    wabs_xquant_kernel<<<1024 + M, 256, 0, stream>>>(w, wsum, wcount / 4, x, xq, xscale, K);
    wquant_kernel<<<2048, 256, 0, stream>>>(w, wsum, wq, wcount / 4, wcount);
    dim3 grid(N / 256, M / 256);
    gemm_i8_kernel<<<grid, 512, 0, stream>>>(xq, wq, xscale, wsum, y, M, N, K, wcount);
}